// Round 2
// baseline (88.004 us; speedup 1.0000x reference)
//
#include <hip/hip_runtime.h>

// O = U X U^H with U = kron of 11 single-qubit gates (2048^2, complex64).
// Kron structure => U@v is 11 radix-2 butterfly stages (strides 1..1024).
// Two kernels:
//  P1 fused_col: W = U X. One block per 2048x8 column strip, all 11 stages
//     in LDS (tile[2048][9] float2 = 147KB, pad->min bank aliasing).
//  P2 rowgate_final: O[i,:] = conj(U) @ W[i,:], fully register-resident
//     (32 float2/lane), bits 0..5 via shfl_xor, bits 6..10 in-register.
// Gates are rebuilt per-block in LDS (trivial cost, saves launches).
// Traffic: 16 + 32 + 32 + 16 = 96 MB, memory-bound.

#define DIM 2048
#define NQ 11

__device__ __forceinline__ float2 cmul(float2 a, float2 b) {
    return make_float2(a.x * b.x - a.y * b.y, a.x * b.y + a.y * b.x);
}

// Compute composite gate g = Rz @ Ry @ Rx for qubit q from weights.
// conj != 0 -> conjugate all entries.
__device__ __forceinline__ void make_gate(const float* __restrict__ w, int q,
                                          int conj, float2* out4) {
    const float WM = 0.632455532033675866f;  // sqrt(2/5) = GAIN * 5^-0.5
    float hx = 0.5f * WM * w[q * 3 + 0];
    float hy = 0.5f * WM * w[q * 3 + 1];
    float hz = 0.5f * WM * w[q * 3 + 2];
    float cx, sx, cy, sy, cz, sz;
    sincosf(hx, &sx, &cx);
    sincosf(hy, &sy, &cy);
    sincosf(hz, &sz, &cz);
    float2 m00 = make_float2(cy * cx,  sy * sx);
    float2 m01 = make_float2(-sy * cx, -cy * sx);
    float2 m10 = make_float2(sy * cx,  -cy * sx);
    float2 m11 = make_float2(cy * cx,  -sy * sx);
    float2 ez  = make_float2(cz, -sz);
    float2 ezc = make_float2(cz,  sz);
    float2 g00 = cmul(ez, m00);
    float2 g01 = cmul(ez, m01);
    float2 g10 = cmul(ezc, m10);
    float2 g11 = cmul(ezc, m11);
    float sgn = conj ? -1.f : 1.f;
    out4[0] = make_float2(g00.x, sgn * g00.y);
    out4[1] = make_float2(g01.x, sgn * g01.y);
    out4[2] = make_float2(g10.x, sgn * g10.y);
    out4[3] = make_float2(g11.x, sgn * g11.y);
}

// P1: full column transform W = U X. Block: all 2048 rows x 8 cols in LDS.
// Row-index bit b (stride 1<<b) corresponds to qubit 10-b.
__global__ __launch_bounds__(1024, 1) void fused_col(
    const float* __restrict__ X, float2* __restrict__ W,
    const float* __restrict__ wt) {
    __shared__ float2 tile[DIM][9];       // pad 8->9: min bank aliasing
    __shared__ float2 gsh[NQ][4];
    int t = threadIdx.x;
    int c0 = blockIdx.x * 8;

    if (t < NQ) make_gate(wt, t, 0, &gsh[t][0]);

    // load: 2048x8 reals, 16 elems/thread
#pragma unroll
    for (int e = 0; e < 16; ++e) {
        int idx = t + e * 1024;
        int r = idx >> 3, c = idx & 7;
        tile[r][c] = make_float2(X[(size_t)r * DIM + c0 + c], 0.f);
    }

    for (int b = 0; b < 11; ++b) {
        int s = 1 << b;
        __syncthreads();   // first iter also covers gate-build + loads
        int q = 10 - b;
        float2 g00 = gsh[q][0], g01 = gsh[q][1];
        float2 g10 = gsh[q][2], g11 = gsh[q][3];
#pragma unroll
        for (int m = 0; m < 8; ++m) {
            int pp = t + m * 1024;        // 8192 pairs total
            int c = pp & 7, pi = pp >> 3;
            int k0 = ((pi >> b) << (b + 1)) | (pi & (s - 1));
            int k1 = k0 + s;
            float2 A = tile[k0][c], B = tile[k1][c];
            float2 n0 = cmul(g00, A), pb = cmul(g01, B);
            float2 n1 = cmul(g10, A), qb = cmul(g11, B);
            tile[k0][c] = make_float2(n0.x + pb.x, n0.y + pb.y);
            tile[k1][c] = make_float2(n1.x + qb.x, n1.y + qb.y);
        }
    }
    __syncthreads();
#pragma unroll
    for (int e = 0; e < 16; ++e) {
        int idx = t + e * 1024;
        int r = idx >> 3, c = idx & 7;
        W[(size_t)r * DIM + c0 + c] = tile[r][c];
    }
}

// P2: O[i,:] = conj(U) @ W[i,:]. One wave per row; lane holds j = 64*r + lane
// for r=0..31. Col bits 0..5 -> shfl_xor (qubits 10..5); col bits 6..10 ->
// in-register strides 1..16 (qubits 4..0). Writes Re(O) (or complex if
// out_size indicates interleaved complex).
__global__ __launch_bounds__(256) void rowgate_final(
    const float2* __restrict__ W, float* __restrict__ Out,
    const float* __restrict__ wt, int writeComplex) {
    __shared__ float2 gsh[NQ][4];
    int t = threadIdx.x;
    if (t < NQ) make_gate(wt, t, 1, &gsh[t][0]);  // conjugated set
    __syncthreads();

    int lane = t & 63;
    int row = blockIdx.x * 4 + (t >> 6);
    const float2* yrow = W + (size_t)row * DIM;

    float2 v[32];
#pragma unroll
    for (int r = 0; r < 32; ++r) v[r] = yrow[64 * r + lane];

    // cross-lane gates: col bit b in 0..5 -> qubit 10-b
#pragma unroll
    for (int b = 0; b < 6; ++b) {
        int q = 10 - b;
        float2 g00 = gsh[q][0], g01 = gsh[q][1];
        float2 g10 = gsh[q][2], g11 = gsh[q][3];
        bool hi = (lane & (1 << b)) != 0;
#pragma unroll
        for (int r = 0; r < 32; ++r) {
            float2 pv;
            pv.x = __shfl_xor(v[r].x, 1 << b);
            pv.y = __shfl_xor(v[r].y, 1 << b);
            float2 a = hi ? pv : v[r];     // bit=0 element
            float2 bb = hi ? v[r] : pv;    // bit=1 element
            float2 lo0 = cmul(g00, a), lo1 = cmul(g01, bb);
            float2 hi0 = cmul(g10, a), hi1 = cmul(g11, bb);
            float2 nlo = make_float2(lo0.x + lo1.x, lo0.y + lo1.y);
            float2 nhi = make_float2(hi0.x + hi1.x, hi0.y + hi1.y);
            v[r] = hi ? nhi : nlo;
        }
    }
    // in-register gates: col bit 6+b -> stride 1<<b in r, qubit 4-b
#pragma unroll
    for (int b = 0; b < 5; ++b) {
        int s = 1 << b;
        int q = 4 - b;
        float2 g00 = gsh[q][0], g01 = gsh[q][1];
        float2 g10 = gsh[q][2], g11 = gsh[q][3];
#pragma unroll
        for (int k0 = 0; k0 < 32; ++k0) {
            if ((k0 & s) == 0) {
                int k1 = k0 + s;
                float2 A = v[k0], B = v[k1];
                float2 n0 = cmul(g00, A), p0 = cmul(g01, B);
                float2 n1 = cmul(g10, A), p1 = cmul(g11, B);
                v[k0] = make_float2(n0.x + p0.x, n0.y + p0.y);
                v[k1] = make_float2(n1.x + p1.x, n1.y + p1.y);
            }
        }
    }

    if (writeComplex) {
        float2* o2 = (float2*)Out;
#pragma unroll
        for (int r = 0; r < 32; ++r)
            o2[(size_t)row * DIM + 64 * r + lane] = v[r];
    } else {
#pragma unroll
        for (int r = 0; r < 32; ++r)
            Out[(size_t)row * DIM + 64 * r + lane] = v[r].x;
    }
}

extern "C" void kernel_launch(void* const* d_in, const int* in_sizes, int n_in,
                              void* d_out, int out_size, void* d_ws,
                              size_t ws_size, hipStream_t stream) {
    const float* X = (const float*)d_in[0];
    const float* wt = (const float*)d_in[1];
    float* out = (float*)d_out;
    float2* W = (float2*)d_ws;  // DIM*DIM complex = 32 MB

    fused_col<<<DIM / 8, 1024, 0, stream>>>(X, W, wt);
    int wc = (out_size >= 2 * DIM * DIM) ? 1 : 0;
    rowgate_final<<<DIM / 4, 256, 0, stream>>>(W, out, wt, wc);
}

// Round 3
// 62.290 us; speedup vs baseline: 1.4128x; 1.4128x over previous
//
#include <hip/hip_runtime.h>

// O = U X U^H, U = kron of 11 single-qubit SU(2) gates (2048^2 complex64).
// Kron structure => each transform = 11 radix-2 butterfly stages (strides
// 1..1024). Two kernels, each does a full 2048-point transform over one
// index with 8 "channels" of the other index per block:
//   colpass: W = U X      (butterfly over row index, 8-column strips)
//   rowpass: O = W conj(U)^T-applied-per-row (butterfly over col index, 8 rows)
// Each kernel: 3 register phases (thread holds 16 elems = 4 bits local):
//   A: bits 7-10 (from global) -> LDS -> M: bits 3-6 -> LDS -> F: bits 0-2.
// LDS layout word(r,c) = 16r + 2c + 8*(r>>4): conflict-free for all phases.
// W stored strip-blocked (2048x8 contiguous per strip) => rowpass loads are
// dense 512B/wave. Traffic ~96 MB total, memory-bound target ~25 us.

#define DIM 2048
#define NQ 11

// float2 index into padded LDS tile: 8r + c + 4*(r>>4); max 16891.
__device__ __forceinline__ int idx2(int r, int c) {
    return (r << 3) + c + ((r >> 4) << 2);
}

__device__ __forceinline__ float2 cmul(float2 a, float2 b) {
    return make_float2(a.x * b.x - a.y * b.y, a.x * b.y + a.y * b.x);
}

// Composite gate g = Rz @ Ry @ Rx for qubit q; conj!=0 -> conjugate entries.
__device__ __forceinline__ void make_gate(const float* __restrict__ w, int q,
                                          int conj, float2* out4) {
    const float WM = 0.632455532033675866f;  // sqrt(2/5)
    float hx = 0.5f * WM * w[q * 3 + 0];
    float hy = 0.5f * WM * w[q * 3 + 1];
    float hz = 0.5f * WM * w[q * 3 + 2];
    float cx, sx, cy, sy, cz, sz;
    sincosf(hx, &sx, &cx);
    sincosf(hy, &sy, &cy);
    sincosf(hz, &sz, &cz);
    float2 m00 = make_float2(cy * cx,  sy * sx);
    float2 m01 = make_float2(-sy * cx, -cy * sx);
    float2 m10 = make_float2(sy * cx,  -cy * sx);
    float2 m11 = make_float2(cy * cx,  -sy * sx);
    float2 ez  = make_float2(cz, -sz);
    float2 ezc = make_float2(cz,  sz);
    float2 g00 = cmul(ez, m00);
    float2 g01 = cmul(ez, m01);
    float2 g10 = cmul(ezc, m10);
    float2 g11 = cmul(ezc, m11);
    float sgn = conj ? -1.f : 1.f;
    out4[0] = make_float2(g00.x, sgn * g00.y);
    out4[1] = make_float2(g01.x, sgn * g01.y);
    out4[2] = make_float2(g10.x, sgn * g10.y);
    out4[3] = make_float2(g11.x, sgn * g11.y);
}

// In-register butterfly: (A,B) <- (g00 A + g01 B, g10 A + g11 B).
__device__ __forceinline__ void bfly(float2& A, float2& B, const float2* g) {
    float2 a = A, b = B;
    A = make_float2(g[0].x * a.x - g[0].y * a.y + g[1].x * b.x - g[1].y * b.y,
                    g[0].x * a.y + g[0].y * a.x + g[1].x * b.y + g[1].y * b.x);
    B = make_float2(g[2].x * a.x - g[2].y * a.y + g[3].x * b.x - g[3].y * b.y,
                    g[2].x * a.y + g[2].y * a.x + g[3].x * b.y + g[3].y * b.x);
}

// One stage over the thread's 16 register elements, local stride ST.
template <int ST>
__device__ __forceinline__ void stage16(float2* v, const float2* g) {
#pragma unroll
    for (int m = 0; m < 16; ++m)
        if (!(m & ST)) bfly(v[m], v[m + ST], g);
}

__device__ __forceinline__ void load_gate(const float2 (*gsh)[4], int q,
                                          float2* g) {
    g[0] = gsh[q][0]; g[1] = gsh[q][1]; g[2] = gsh[q][2]; g[3] = gsh[q][3];
}

// ---------------- K1: W = U X (column transform, 8-col strip) --------------
__global__ __launch_bounds__(1024, 1) void colpass(
    const float* __restrict__ X, float2* __restrict__ W,
    const float* __restrict__ wt) {
    __shared__ float2 lds[16892];
    __shared__ float2 gsh[NQ][4];
    int t = threadIdx.x;
    if (t < NQ) make_gate(wt, t, 0, &gsh[t][0]);
    __syncthreads();  // B0: gates ready (cheap, nothing else pending)

    int c = t & 7, u = t >> 3;
    int c0 = blockIdx.x * 8;

    // Phase A: r = u + 128m (bits 7..10 local -> qubits 3,2,1,0). X is real.
    float xr[16];
#pragma unroll
    for (int m = 0; m < 16; ++m)
        xr[m] = X[(size_t)(u + (m << 7)) * DIM + c0 + c];

    float2 v[16];
    float2 g[4];
    load_gate(gsh, 3, g);  // bit 7 (stride-1 in m), real inputs
#pragma unroll
    for (int m = 0; m < 16; m += 2) {
        float a = xr[m], b = xr[m + 1];
        v[m]     = make_float2(g[0].x * a + g[1].x * b, g[0].y * a + g[1].y * b);
        v[m + 1] = make_float2(g[2].x * a + g[3].x * b, g[2].y * a + g[3].y * b);
    }
    load_gate(gsh, 2, g); stage16<2>(v, g);   // bit 8
    load_gate(gsh, 1, g); stage16<4>(v, g);   // bit 9
    load_gate(gsh, 0, g); stage16<8>(v, g);   // bit 10

#pragma unroll
    for (int m = 0; m < 16; ++m)
        lds[idx2(u + (m << 7), c)] = v[m];
    __syncthreads();  // B1

    // Phase M: r = (u&7) + 8m + 128*(u>>3) (bits 3..6 -> qubits 7,6,5,4).
    int uLo = u & 7, uHi = u >> 3;
#pragma unroll
    for (int m = 0; m < 16; ++m)
        v[m] = lds[idx2(uLo + (m << 3) + (uHi << 7), c)];
    load_gate(gsh, 7, g); stage16<1>(v, g);   // bit 3
    load_gate(gsh, 6, g); stage16<2>(v, g);   // bit 4
    load_gate(gsh, 5, g); stage16<4>(v, g);   // bit 5
    load_gate(gsh, 4, g); stage16<8>(v, g);   // bit 6
#pragma unroll
    for (int m = 0; m < 16; ++m)
        lds[idx2(uLo + (m << 3) + (uHi << 7), c)] = v[m];
    __syncthreads();  // B2

    // Phase F: r = m + 16u (bits 0..2 -> qubits 10,9,8).
#pragma unroll
    for (int m = 0; m < 16; ++m)
        v[m] = lds[idx2(m + (u << 4), c)];
    load_gate(gsh, 10, g); stage16<1>(v, g);  // bit 0
    load_gate(gsh, 9, g);  stage16<2>(v, g);  // bit 1
    load_gate(gsh, 8, g);  stage16<4>(v, g);  // bit 2

    // Store strip-blocked: W_strip[blk][r][c], r = m + 16u.
    float2* ws = W + (size_t)blockIdx.x * (DIM * 8);
#pragma unroll
    for (int m = 0; m < 16; ++m)
        ws[(size_t)(m + (u << 4)) * 8 + c] = v[m];
}

// ------------- K2: O rows = conj(U) applied along columns of W -------------
__global__ __launch_bounds__(1024, 1) void rowpass(
    const float2* __restrict__ W, float* __restrict__ Out,
    const float* __restrict__ wt, int writeComplex) {
    __shared__ float2 lds[16892];
    __shared__ float2 gsh[NQ][4];
    int t = threadIdx.x;
    if (t < NQ) make_gate(wt, t, 1, &gsh[t][0]);  // conjugated gates
    __syncthreads();

    int rv = t & 7, u = t >> 3;     // rv = row within 8-row group
    int r0 = blockIdx.x * 8;

    // Phase A: j = u + 128m. Strip s = (u>>3) + 16m; dense 512B/wave loads.
    float2 v[16];
    int uLo3 = u & 7, uHi = u >> 3;
#pragma unroll
    for (int m = 0; m < 16; ++m)
        v[m] = W[(size_t)(uHi + (m << 4)) * (DIM * 8) +
                 (size_t)(r0 + rv) * 8 + uLo3];

    float2 g[4];
    load_gate(gsh, 3, g); stage16<1>(v, g);   // j bit 7
    load_gate(gsh, 2, g); stage16<2>(v, g);   // j bit 8
    load_gate(gsh, 1, g); stage16<4>(v, g);   // j bit 9
    load_gate(gsh, 0, g); stage16<8>(v, g);   // j bit 10
#pragma unroll
    for (int m = 0; m < 16; ++m)
        lds[idx2(u + (m << 7), rv)] = v[m];
    __syncthreads();

    // Phase M: j = (u&7) + 8m + 128*(u>>3) (bits 3..6 -> qubits 7,6,5,4).
#pragma unroll
    for (int m = 0; m < 16; ++m)
        v[m] = lds[idx2(uLo3 + (m << 3) + (uHi << 7), rv)];
    load_gate(gsh, 7, g); stage16<1>(v, g);
    load_gate(gsh, 6, g); stage16<2>(v, g);
    load_gate(gsh, 5, g); stage16<4>(v, g);
    load_gate(gsh, 4, g); stage16<8>(v, g);
#pragma unroll
    for (int m = 0; m < 16; ++m)
        lds[idx2(uLo3 + (m << 3) + (uHi << 7), rv)] = v[m];
    __syncthreads();

    // Phase F: j = m + 16u (bits 0..2 -> qubits 10,9,8).
#pragma unroll
    for (int m = 0; m < 16; ++m)
        v[m] = lds[idx2(m + (u << 4), rv)];
    load_gate(gsh, 10, g); stage16<1>(v, g);
    load_gate(gsh, 9, g);  stage16<2>(v, g);
    load_gate(gsh, 8, g);  stage16<4>(v, g);

    // Thread holds 16 consecutive j = [16u, 16u+15] of row r0+rv.
    if (!writeComplex) {
        float4* op = (float4*)(Out + (size_t)(r0 + rv) * DIM + (u << 4));
        op[0] = make_float4(v[0].x, v[1].x, v[2].x, v[3].x);
        op[1] = make_float4(v[4].x, v[5].x, v[6].x, v[7].x);
        op[2] = make_float4(v[8].x, v[9].x, v[10].x, v[11].x);
        op[3] = make_float4(v[12].x, v[13].x, v[14].x, v[15].x);
    } else {
        float2* o2 = (float2*)Out + (size_t)(r0 + rv) * DIM + (u << 4);
#pragma unroll
        for (int m = 0; m < 16; ++m) o2[m] = v[m];
    }
}

extern "C" void kernel_launch(void* const* d_in, const int* in_sizes, int n_in,
                              void* d_out, int out_size, void* d_ws,
                              size_t ws_size, hipStream_t stream) {
    const float* X = (const float*)d_in[0];
    const float* wt = (const float*)d_in[1];
    float* out = (float*)d_out;
    float2* W = (float2*)d_ws;  // 32 MB strip-blocked intermediate

    colpass<<<DIM / 8, 1024, 0, stream>>>(X, W, wt);
    int wc = (out_size >= 2 * DIM * DIM) ? 1 : 0;
    rowpass<<<DIM / 8, 1024, 0, stream>>>(W, out, wt, wc);
}